// Round 4
// baseline (424.712 us; speedup 1.0000x reference)
//
#include <hip/hip_runtime.h>
#include <stdint.h>

#define NB 8
#define NC 256
#define NE 128
#define NHW 4096

typedef __bf16 v8bf __attribute__((ext_vector_type(8)));
typedef float v4f __attribute__((ext_vector_type(4)));
typedef float v16f __attribute__((ext_vector_type(16)));
typedef unsigned int v4u __attribute__((ext_vector_type(4)));

#if __has_builtin(__builtin_amdgcn_exp2f)
#define EXP2F(x) __builtin_amdgcn_exp2f(x)
#else
#define EXP2F(x) exp2f(x)
#endif

// fp32 -> bf16 round-to-nearest-even (bit trick; finite inputs only)
__device__ __forceinline__ unsigned short f2bf(float x) {
    union { float f; unsigned int u; } v; v.f = x;
    unsigned int r = v.u + 0x7fffu + ((v.u >> 16) & 1u);
    return (unsigned short)(r >> 16);
}

// pack two fp32 -> bf16x2 with round-half-up (cheap: 5 VALU); fine for P in (0,1]
__device__ __forceinline__ unsigned int pack_bf2_ru(float a, float b) {
    union { float f; unsigned int u; } va, vb; va.f = a; vb.f = b;
    return ((va.u + 0x8000u) >> 16) | ((vb.u + 0x8000u) & 0xffff0000u);
}

// ---------------- K0: cast weights to bf16. Wbf[e][c], e<128 = w_theta * (scale*log2e), e>=128 = w_phi
__global__ __launch_bounds__(256) void cast_w_kernel(const float* __restrict__ wt,
                                                     const float* __restrict__ wp,
                                                     unsigned short* __restrict__ Wbf) {
    int i = blockIdx.x * 256 + threadIdx.x;                 // 0..65535
    const float QS = 0.08838834764831845f * 1.4426950408889634f; // 1/sqrt(128) * log2(e)
    float v = (i < 32768) ? wt[i] * QS : wp[i - 32768];
    Wbf[i] = f2bf(v);
}

// ---------------- K1: projection (+ fused V cast). Per block: batch b, 64-q tile.
__global__ __launch_bounds__(256, 2) void proj_kernel(const float* __restrict__ l,
                                                      const unsigned short* __restrict__ Wbf,
                                                      unsigned short* __restrict__ Qbf,
                                                      unsigned short* __restrict__ Kbf,
                                                      unsigned short* __restrict__ Vbf) {
    __shared__ __align__(16) unsigned short A[64][264];     // [q][c], +8 pad
    const int tid = threadIdx.x;
    const int b = blockIdx.x & 7;
    const int qt = (blockIdx.x >> 3) << 6;
    const float* lb = l + ((size_t)b * NC * NHW + qt);

    for (int s = 0; s < 16; ++s) {
        int f = tid + s * 256;
        int c = f >> 4, j = f & 15;
        float4 v = *(const float4*)(lb + (size_t)c * NHW + j * 4);
        ushort4 o4;
        o4.x = f2bf(v.x); o4.y = f2bf(v.y); o4.z = f2bf(v.z); o4.w = f2bf(v.w);
        A[j * 4 + 0][c] = o4.x;
        A[j * 4 + 1][c] = o4.y;
        A[j * 4 + 2][c] = o4.z;
        A[j * 4 + 3][c] = o4.w;
        *(ushort4*)(Vbf + (size_t)b * NC * NHW + (size_t)c * NHW + qt + j * 4) = o4;
    }
    __syncthreads();

    const int w = tid >> 6, L = tid & 63;
    const int l15 = L & 15, q4 = L >> 4;
    const v4f vz = {0.f, 0.f, 0.f, 0.f};
    v4f acc[4][4];
    for (int mt = 0; mt < 4; ++mt)
        for (int nt = 0; nt < 4; ++nt) acc[mt][nt] = vz;

    for (int kf = 0; kf < 8; ++kf) {
        int kc = kf * 32 + q4 * 8;
        v8bf a[4], bb[4];
        for (int mt = 0; mt < 4; ++mt)
            a[mt] = *(const v8bf*)&A[mt * 16 + l15][kc];
        for (int nt = 0; nt < 4; ++nt)
            bb[nt] = *(const v8bf*)(Wbf + (w * 64 + nt * 16 + l15) * 256 + kc);
        for (int mt = 0; mt < 4; ++mt)
            for (int nt = 0; nt < 4; ++nt)
                acc[mt][nt] = __builtin_amdgcn_mfma_f32_16x16x32_bf16(a[mt], bb[nt], acc[mt][nt], 0, 0, 0);
    }

    unsigned short* dst = (w < 2) ? Qbf : Kbf;
    const int ebase = (w & 1) * 64;
    for (int mt = 0; mt < 4; ++mt)
        for (int nt = 0; nt < 4; ++nt)
            for (int r = 0; r < 4; ++r) {
                int q = qt + mt * 16 + q4 * 4 + r;
                int e = ebase + nt * 16 + l15;
                dst[((size_t)b * NHW + q) * NE + e] = f2bf(acc[mt][nt][r]);
            }
}

// ---------------- K2: flash attention, 32x32x16. q-tile 64, k-tile 64, 4 waves.
// QK: wave (qh,kh) computes S^T quarter; P^T B-frags assembled IN REGS (lane^32
// exchange) then shared via 2 conflict-free ds_write_b128 per wave.
// PV: wave owns 64-c slice (o = 64 AGPR, not 128) -> room for 48-reg prefetch.
// Prefetch: tile i+1 global loads issued AFTER B2, consumed after next B1 ->
// vmcnt(0) drain lands post-compute (latency hidden). 3 barriers/iter.
// LDS 56K: Ku[64][128]swz | Vu[256][64]swz | Pu 8 tiles x 1KB (B-frag layout).
__global__ __launch_bounds__(256, 2) void attn_kernel(const unsigned short* __restrict__ Qbf,
                                                      const unsigned short* __restrict__ Kbf,
                                                      const unsigned short* __restrict__ Vbf,
                                                      float* __restrict__ out) {
    __shared__ __align__(16) unsigned char smem[57344];
    unsigned short* Ku = (unsigned short*)smem;             // [64][128] xor16-swz
    unsigned short* Vu = (unsigned short*)(smem + 16384);   // [256][64] xor8-swz
    unsigned short* Pu = (unsigned short*)(smem + 49152);   // [8 tiles][64 units x 16B]

    const int tid = threadIdx.x;
    const int b = blockIdx.x & 7;                           // batch -> XCD
    const int qt64 = (blockIdx.x >> 3) << 6;
    const int w = tid >> 6;
    const int L = tid & 63;
    const int l31 = L & 31, hi = L >> 5;
    const int qh = w >> 1, kh = w & 1;
    const int x15 = l31 & 15, x7 = l31 & 7;

    const unsigned short* Kb = Kbf + (size_t)b * NHW * NE;
    const unsigned short* Vb = Vbf + (size_t)b * NC * NHW;

    // Q B-frags (regs, whole kernel): B[k=e][n=q], n=l31 -> q row qh*32+l31
    v8bf bq[8];
    {
        const unsigned short* qrow = Qbf + ((size_t)b * NHW + qt64 + qh * 32 + l31) * NE + hi * 8;
#pragma unroll
        for (int ef = 0; ef < 8; ++ef)
            bq[ef] = *(const v8bf*)(qrow + ef * 16);
    }

    v16f o[2][2];                                           // [c2][qt] 64 AGPR
#pragma unroll
    for (int c2 = 0; c2 < 2; ++c2)
#pragma unroll
        for (int qt = 0; qt < 2; ++qt)
#pragma unroll
            for (int r = 0; r < 16; ++r) o[c2][qt][r] = 0.f;
    float lacc = 0.f;

    uint4 pfk[4], pfv[8];                                   // prefetch regs (48 VGPR)
#define LOAD_TILE(k0)                                                          \
    {                                                                          \
        _Pragma("unroll") for (int s = 0; s < 4; ++s) {                        \
            int idx = tid + s * 256, r = idx >> 4, c8 = idx & 15;              \
            pfk[s] = *(const uint4*)(Kb + (size_t)((k0) + r) * NE + c8 * 8);   \
        }                                                                      \
        _Pragma("unroll") for (int s = 0; s < 8; ++s) {                        \
            int idx = tid + s * 256, c = idx >> 3, u = idx & 7;                \
            pfv[s] = *(const uint4*)(Vb + (size_t)c * NHW + (k0) + u * 8);     \
        }                                                                      \
    }

    LOAD_TILE(0);

    for (int it = 0; it < 64; ++it) {
        __syncthreads();                                    // B1: prev reads done + prefetch drained
        // write prefetched tile to LDS (swizzled)
#pragma unroll
        for (int s = 0; s < 4; ++s) {
            int idx = tid + s * 256, r = idx >> 4, c8 = idx & 15;
            *(uint4*)&Ku[r * 128 + ((c8 ^ (r & 15)) * 8)] = pfk[s];
        }
#pragma unroll
        for (int s = 0; s < 8; ++s) {
            int idx = tid + s * 256, c = idx >> 3, u = idx & 7;
            *(uint4*)&Vu[c * 64 + ((u ^ (c & 7)) * 8)] = pfv[s];
        }
        __syncthreads();                                    // B2: tile visible
        // issue next tile's loads NOW -> latency overlapped by QK+PV compute
        LOAD_TILE(((it + 1) & 63) << 6);

        // ---- QK: S^T (k rows kh*32.., q cols qh*32..), two 4-deep MFMA chains
        v16f s0v, s1v;
#pragma unroll
        for (int r = 0; r < 16; ++r) { s0v[r] = 0.f; s1v[r] = 0.f; }
        {
            const unsigned short* krow = Ku + (kh * 32 + l31) * 128;
#pragma unroll
            for (int ef = 0; ef < 4; ++ef) {
                v8bf ak0 = *(const v8bf*)(krow + (((4 * ef + hi) ^ x15) * 8));
                v8bf ak1 = *(const v8bf*)(krow + (((4 * ef + 2 + hi) ^ x15) * 8));
                s0v = __builtin_amdgcn_mfma_f32_32x32x16_bf16(ak0, bq[2 * ef], s0v, 0, 0, 0);
                s1v = __builtin_amdgcn_mfma_f32_32x32x16_bf16(ak1, bq[2 * ef + 1], s1v, 0, 0, 0);
            }
        }

        // ---- softmax: p = 2^s; per-lane row-sum partial for q-col qh*32+l31
        float p[16];
#pragma unroll
        for (int r = 0; r < 16; ++r) p[r] = EXP2F(s0v[r] + s1v[r]);
#pragma unroll
        for (int r = 0; r < 16; ++r) lacc += p[r];
        // assemble P^T B-frags (verified R3 mapping): frag kf covers
        // k = kh*32 + kf*16 + hi*8 + j, n = l31.
        unsigned int pk2[8], px2[8];
#pragma unroll
        for (int t = 0; t < 8; ++t) pk2[t] = pack_bf2_ru(p[2 * t], p[2 * t + 1]);
#pragma unroll
        for (int t = 0; t < 8; ++t) px2[t] = (unsigned int)__shfl_xor((int)pk2[t], 32);
        union { v4u u; v8bf b; } f0, f1;
        if (hi == 0) {
            f0.u = (v4u){pk2[0], pk2[1], px2[0], px2[1]};
            f1.u = (v4u){pk2[4], pk2[5], px2[4], px2[5]};
        } else {
            f0.u = (v4u){px2[2], px2[3], pk2[2], pk2[3]};
            f1.u = (v4u){px2[6], px2[7], pk2[6], pk2[7]};
        }
        // share P: tile t = K*2 + qh where K = kh*2 + {0,1}; unit = l31*2+hi
        {
            int u16 = (l31 * 2 + hi) * 8;
            *(v4u*)&Pu[(kh * 4 + qh) * 512 + u16] = f0.u;
            *(v4u*)&Pu[(kh * 4 + 2 + qh) * 512 + u16] = f1.u;
        }
        __syncthreads();                                    // B3: P visible

        // ---- PV: wave owns c in [w*64, w*64+64); o[c2][qt] rotate (dep dist 4)
#pragma unroll
        for (int K = 0; K < 4; ++K) {
            int u16 = (l31 * 2 + hi) * 8;
            v8bf bp0 = *(const v8bf*)&Pu[(K * 2 + 0) * 512 + u16];
            v8bf bp1 = *(const v8bf*)&Pu[(K * 2 + 1) * 512 + u16];
#pragma unroll
            for (int c2 = 0; c2 < 2; ++c2) {
                int c = (w * 2 + c2) * 32 + l31;
                v8bf av = *(const v8bf*)&Vu[c * 64 + (((K * 2 + hi) ^ x7) * 8)];
                o[c2][0] = __builtin_amdgcn_mfma_f32_32x32x16_bf16(av, bp0, o[c2][0], 0, 0, 0);
                o[c2][1] = __builtin_amdgcn_mfma_f32_32x32x16_bf16(av, bp1, o[c2][1], 0, 0, 0);
            }
        }
    }

    // ---- epilogue: row sums. lane covers its (kh,hi) rows; +partner hi, then kh via LDS
    float tot = lacc + __shfl_xor(lacc, 32);
    __syncthreads();
    float* red = (float*)(smem + 49152);                    // reuse Pu: [4 waves][32]
    if (hi == 0) red[w * 32 + l31] = tot;
    __syncthreads();
    const float inv0 = 1.0f / (red[0 * 32 + l31] + red[1 * 32 + l31]);  // qt=0: waves 0,1
    const float inv1 = 1.0f / (red[2 * 32 + l31] + red[3 * 32 + l31]);  // qt=1: waves 2,3

    // ---- store: D[m=c][n=q]; col=l31 -> q = qt*32+l31 (coalesced), row -> c
    float* ob = out + (size_t)b * NC * NHW + qt64;
#pragma unroll
    for (int c2 = 0; c2 < 2; ++c2)
#pragma unroll
        for (int r = 0; r < 16; ++r) {
            int c = w * 64 + c2 * 32 + (r & 3) + 8 * (r >> 2) + 4 * hi;
            ob[(size_t)c * NHW + 0 * 32 + l31] = o[c2][0][r] * inv0;
            ob[(size_t)c * NHW + 1 * 32 + l31] = o[c2][1][r] * inv1;
        }
}

extern "C" void kernel_launch(void* const* d_in, const int* in_sizes, int n_in,
                              void* d_out, int out_size, void* d_ws, size_t ws_size,
                              hipStream_t stream) {
    const float* l  = (const float*)d_in[0];
    const float* wt = (const float*)d_in[1];
    const float* wp = (const float*)d_in[2];
    float* out = (float*)d_out;

    char* ws = (char*)d_ws;
    unsigned short* Wbf = (unsigned short*)ws;                          // 131072 B
    unsigned short* Qbf = (unsigned short*)(ws + 131072);               // 8 MB
    unsigned short* Kbf = (unsigned short*)(ws + 131072 + 8388608);     // 8 MB
    unsigned short* Vbf = (unsigned short*)(ws + 131072 + 16777216);    // 16 MB

    hipLaunchKernelGGL(cast_w_kernel, dim3(256), dim3(256), 0, stream, wt, wp, Wbf);
    hipLaunchKernelGGL(proj_kernel,   dim3(512), dim3(256), 0, stream, l, Wbf, Qbf, Kbf, Vbf);
    hipLaunchKernelGGL(attn_kernel,   dim3(512), dim3(256), 0, stream, Qbf, Kbf, Vbf, out);
}

// Round 5
// 237.139 us; speedup vs baseline: 1.7910x; 1.7910x over previous
//
#include <hip/hip_runtime.h>
#include <stdint.h>

#define NB 8
#define NC 256
#define NE 128
#define NHW 4096

typedef __bf16 v8bf __attribute__((ext_vector_type(8)));
typedef float v4f __attribute__((ext_vector_type(4)));
typedef float v16f __attribute__((ext_vector_type(16)));

#if __has_builtin(__builtin_amdgcn_exp2f)
#define EXP2F(x) __builtin_amdgcn_exp2f(x)
#else
#define EXP2F(x) exp2f(x)
#endif

// fp32 -> bf16 round-to-nearest-even (bit trick; finite inputs only)
__device__ __forceinline__ unsigned short f2bf(float x) {
    union { float f; unsigned int u; } v; v.f = x;
    unsigned int r = v.u + 0x7fffu + ((v.u >> 16) & 1u);
    return (unsigned short)(r >> 16);
}

// ---------------- K0: cast weights to bf16. Wbf[e][c], e<128 = w_theta * (scale*log2e), e>=128 = w_phi
__global__ __launch_bounds__(256) void cast_w_kernel(const float* __restrict__ wt,
                                                     const float* __restrict__ wp,
                                                     unsigned short* __restrict__ Wbf) {
    int i = blockIdx.x * 256 + threadIdx.x;                 // 0..65535
    const float QS = 0.08838834764831845f * 1.4426950408889634f; // 1/sqrt(128) * log2(e)
    float v = (i < 32768) ? wt[i] * QS : wp[i - 32768];
    Wbf[i] = f2bf(v);
}

// ---------------- K1: projection (+ fused V cast). Per block: batch b, 64-q tile.
__global__ __launch_bounds__(256, 2) void proj_kernel(const float* __restrict__ l,
                                                      const unsigned short* __restrict__ Wbf,
                                                      unsigned short* __restrict__ Qbf,
                                                      unsigned short* __restrict__ Kbf,
                                                      unsigned short* __restrict__ Vbf) {
    __shared__ __align__(16) unsigned short A[64][264];     // [q][c], +8 pad
    const int tid = threadIdx.x;
    const int b = blockIdx.x & 7;
    const int qt = (blockIdx.x >> 3) << 6;
    const float* lb = l + ((size_t)b * NC * NHW + qt);

    for (int s = 0; s < 16; ++s) {
        int f = tid + s * 256;
        int c = f >> 4, j = f & 15;
        float4 v = *(const float4*)(lb + (size_t)c * NHW + j * 4);
        ushort4 o4;
        o4.x = f2bf(v.x); o4.y = f2bf(v.y); o4.z = f2bf(v.z); o4.w = f2bf(v.w);
        A[j * 4 + 0][c] = o4.x;
        A[j * 4 + 1][c] = o4.y;
        A[j * 4 + 2][c] = o4.z;
        A[j * 4 + 3][c] = o4.w;
        *(ushort4*)(Vbf + (size_t)b * NC * NHW + (size_t)c * NHW + qt + j * 4) = o4;
    }
    __syncthreads();

    const int w = tid >> 6, L = tid & 63;
    const int l15 = L & 15, q4 = L >> 4;
    const v4f vz = {0.f, 0.f, 0.f, 0.f};
    v4f acc[4][4];
    for (int mt = 0; mt < 4; ++mt)
        for (int nt = 0; nt < 4; ++nt) acc[mt][nt] = vz;

    for (int kf = 0; kf < 8; ++kf) {
        int kc = kf * 32 + q4 * 8;
        v8bf a[4], bb[4];
        for (int mt = 0; mt < 4; ++mt)
            a[mt] = *(const v8bf*)&A[mt * 16 + l15][kc];
        for (int nt = 0; nt < 4; ++nt)
            bb[nt] = *(const v8bf*)(Wbf + (w * 64 + nt * 16 + l15) * 256 + kc);
        for (int mt = 0; mt < 4; ++mt)
            for (int nt = 0; nt < 4; ++nt)
                acc[mt][nt] = __builtin_amdgcn_mfma_f32_16x16x32_bf16(a[mt], bb[nt], acc[mt][nt], 0, 0, 0);
    }

    unsigned short* dst = (w < 2) ? Qbf : Kbf;
    const int ebase = (w & 1) * 64;
    for (int mt = 0; mt < 4; ++mt)
        for (int nt = 0; nt < 4; ++nt)
            for (int r = 0; r < 4; ++r) {
                int q = qt + mt * 16 + q4 * 4 + r;
                int e = ebase + nt * 16 + l15;
                dst[((size_t)b * NHW + q) * NE + e] = f2bf(acc[mt][nt][r]);
            }
}

// ---------------- K2: flash attention, 32x32x16, q-tile 64, k-tile 64, 4 waves.
// QK: S[q][k], A=Q regs (lane m=q), B=K from swizzled LDS (lane n=kcol).
//     wave (qh=w>>1, kh=w&1) -> S quarter [32q x 32k]. 8 MFMAs in 2 chains.
// P:  C/D (lane=kcol, rows=q) -> b16 scatter into Pu[q][k] (xor8-swizzled units).
// PV: O^T = V*P^T, A=V LDS (lane m=c), B=P^T LDS (lane n=q); wave (qhp=w&1,
//     ctb=(w>>1)*4) -> 4 o-tiles, 64 AGPR. C/D lane = q-col -> coalesced stores.
// Staging loads issued BEFORE B1 -> overlap prev iter's PV. No cross-iter arrays.
// LDS 56K: Ku[64][128]xor16 | Vu[256][64]xor8 | Pu[64][64]xor8. 3 barriers/iter.
__global__ __launch_bounds__(256, 2) void attn_kernel(const unsigned short* __restrict__ Qbf,
                                                      const unsigned short* __restrict__ Kbf,
                                                      const unsigned short* __restrict__ Vbf,
                                                      float* __restrict__ out) {
    __shared__ __align__(16) unsigned char smem[57344];
    unsigned short* Ku = (unsigned short*)smem;             // [64][128] xor16-swz
    unsigned short* Vu = (unsigned short*)(smem + 16384);   // [256][64] xor8-swz
    unsigned short* Pu = (unsigned short*)(smem + 49152);   // [64][64]  xor8-swz
    float* red = (float*)(smem + 49152);                    // epilogue overlay [4][32]

    const int tid = threadIdx.x;
    const int b = blockIdx.x & 7;                           // batch -> XCD affinity
    const int qt64 = (blockIdx.x >> 3) << 6;
    const int w = tid >> 6;
    const int L = tid & 63;
    const int l31 = L & 31, hi = L >> 5;
    const int qh = w >> 1, kh = w & 1;                      // QK roles
    const int qhp = w & 1, ctb = (w >> 1) * 4;              // PV roles

    const unsigned short* Kb = Kbf + (size_t)b * NHW * NE;
    const unsigned short* Vb = Vbf + (size_t)b * NC * NHW;

    // Q A-frags (whole kernel): A[m=q=l31][k=e], frag kf: e = kf*16 + hi*8 + j
    v8bf aq[8];
    {
        const unsigned short* qrow = Qbf + ((size_t)b * NHW + qt64 + qh * 32 + l31) * NE + hi * 8;
#pragma unroll
        for (int kf = 0; kf < 8; ++kf)
            aq[kf] = *(const v8bf*)(qrow + kf * 16);
    }

    v16f o[4];
#pragma unroll
    for (int ci = 0; ci < 4; ++ci)
#pragma unroll
        for (int r = 0; r < 16; ++r) o[ci][r] = 0.f;
    float lacc[16];
#pragma unroll
    for (int r = 0; r < 16; ++r) lacc[r] = 0.f;

    const int kcol = kh * 32 + l31;                         // this lane's S column
    const int xk = l31 & 15;

    for (int it = 0; it < 64; ++it) {
        const int k0 = it << 6;
        // ---- issue this tile's global loads NOW (overlaps prev iter's PV MFMAs)
        uint4 sk0, sk1, sk2, sk3, sv0, sv1, sv2, sv3, sv4, sv5, sv6, sv7;
        {
            int r0 = tid >> 4, c8 = tid & 15;               // K: rows r0, r0+16, +32, +48
            sk0 = *(const uint4*)(Kb + (size_t)(k0 + r0) * NE + c8 * 8);
            sk1 = *(const uint4*)(Kb + (size_t)(k0 + r0 + 16) * NE + c8 * 8);
            sk2 = *(const uint4*)(Kb + (size_t)(k0 + r0 + 32) * NE + c8 * 8);
            sk3 = *(const uint4*)(Kb + (size_t)(k0 + r0 + 48) * NE + c8 * 8);
            int c0 = tid >> 3, u = tid & 7;                 // V: rows c0 + 32*s
            sv0 = *(const uint4*)(Vb + (size_t)(c0 + 0) * NHW + k0 + u * 8);
            sv1 = *(const uint4*)(Vb + (size_t)(c0 + 32) * NHW + k0 + u * 8);
            sv2 = *(const uint4*)(Vb + (size_t)(c0 + 64) * NHW + k0 + u * 8);
            sv3 = *(const uint4*)(Vb + (size_t)(c0 + 96) * NHW + k0 + u * 8);
            sv4 = *(const uint4*)(Vb + (size_t)(c0 + 128) * NHW + k0 + u * 8);
            sv5 = *(const uint4*)(Vb + (size_t)(c0 + 160) * NHW + k0 + u * 8);
            sv6 = *(const uint4*)(Vb + (size_t)(c0 + 192) * NHW + k0 + u * 8);
            sv7 = *(const uint4*)(Vb + (size_t)(c0 + 224) * NHW + k0 + u * 8);
        }
        __syncthreads();                                    // B1: prev LDS reads done
        {
            int r0 = tid >> 4, c8 = tid & 15;
            *(uint4*)&Ku[(r0 + 0) * 128 + ((c8 ^ ((r0 + 0) & 15)) * 8)] = sk0;
            *(uint4*)&Ku[(r0 + 16) * 128 + ((c8 ^ ((r0 + 16) & 15)) * 8)] = sk1;
            *(uint4*)&Ku[(r0 + 32) * 128 + ((c8 ^ ((r0 + 32) & 15)) * 8)] = sk2;
            *(uint4*)&Ku[(r0 + 48) * 128 + ((c8 ^ ((r0 + 48) & 15)) * 8)] = sk3;
            int c0 = tid >> 3, u = tid & 7;
            *(uint4*)&Vu[(c0 + 0) * 64 + ((u ^ ((c0 + 0) & 7)) * 8)] = sv0;
            *(uint4*)&Vu[(c0 + 32) * 64 + ((u ^ ((c0 + 32) & 7)) * 8)] = sv1;
            *(uint4*)&Vu[(c0 + 64) * 64 + ((u ^ ((c0 + 64) & 7)) * 8)] = sv2;
            *(uint4*)&Vu[(c0 + 96) * 64 + ((u ^ ((c0 + 96) & 7)) * 8)] = sv3;
            *(uint4*)&Vu[(c0 + 128) * 64 + ((u ^ ((c0 + 128) & 7)) * 8)] = sv4;
            *(uint4*)&Vu[(c0 + 160) * 64 + ((u ^ ((c0 + 160) & 7)) * 8)] = sv5;
            *(uint4*)&Vu[(c0 + 192) * 64 + ((u ^ ((c0 + 192) & 7)) * 8)] = sv6;
            *(uint4*)&Vu[(c0 + 224) * 64 + ((u ^ ((c0 + 224) & 7)) * 8)] = sv7;
        }
        __syncthreads();                                    // B2: tile visible

        // ---- QK: S quarter [32q x 32k]; two 4-deep chains
        v16f sa, sb;
#pragma unroll
        for (int r = 0; r < 16; ++r) { sa[r] = 0.f; sb[r] = 0.f; }
        {
            const unsigned short* krow = Ku + kcol * 128;
#pragma unroll
            for (int ef = 0; ef < 4; ++ef) {
                v8bf bk0 = *(const v8bf*)(krow + (((2 * ef + hi) ^ xk) * 8));
                v8bf bk1 = *(const v8bf*)(krow + (((2 * (ef + 4) + hi) ^ xk) * 8));
                sa = __builtin_amdgcn_mfma_f32_32x32x16_bf16(aq[ef], bk0, sa, 0, 0, 0);
                sb = __builtin_amdgcn_mfma_f32_32x32x16_bf16(aq[ef + 4], bk1, sb, 0, 0, 0);
            }
        }

        // ---- softmax + P scatter (C/D rows q = qh*32 + R(r)+4hi, col = kcol)
#pragma unroll
        for (int r = 0; r < 16; ++r) {
            float p = EXP2F(sa[r] + sb[r]);
            lacc[r] += p;
            int q = qh * 32 + (r & 3) + 8 * (r >> 2) + 4 * hi;
            Pu[q * 64 + (((kcol >> 3) ^ (q & 7)) * 8) + (kcol & 7)] = f2bf(p);
        }
        __syncthreads();                                    // B3: P visible

        // ---- PV: O^T tiles [32c x 32q]; A=V, B=P^T; o[ci] dep distance 4
        v8bf bp[4];
        {
            int qrow = qhp * 32 + l31;
            const unsigned short* prow = Pu + qrow * 64;
            int xq = qrow & 7;
#pragma unroll
            for (int kf = 0; kf < 4; ++kf)
                bp[kf] = *(const v8bf*)(prow + (((kf * 2 + hi) ^ xq) * 8));
        }
#pragma unroll
        for (int kf = 0; kf < 4; ++kf)
#pragma unroll
            for (int ci = 0; ci < 4; ++ci) {
                int c = (ctb + ci) * 32 + l31;
                v8bf av = *(const v8bf*)&Vu[c * 64 + (((kf * 2 + hi) ^ (c & 7)) * 8)];
                o[ci] = __builtin_amdgcn_mfma_f32_32x32x16_bf16(av, bp[kf], o[ci], 0, 0, 0);
            }
    }
    __syncthreads();                                        // last PV reads done

    // ---- row sums: reduce over the 32 k-cols held across l31 lanes (per half)
#pragma unroll
    for (int r = 0; r < 16; ++r) {
        float v = lacc[r];
        v += __shfl_xor(v, 1);
        v += __shfl_xor(v, 2);
        v += __shfl_xor(v, 4);
        v += __shfl_xor(v, 8);
        v += __shfl_xor(v, 16);
        lacc[r] = v;
    }
    if (l31 == 0) {
#pragma unroll
        for (int r = 0; r < 16; ++r) {
            int q32 = (r & 3) + 8 * (r >> 2) + 4 * hi;
            red[(qh * 2 + kh) * 32 + q32] = lacc[r];
        }
    }
    __syncthreads();
    const float invq = 1.0f / (red[(qhp * 2) * 32 + l31] + red[(qhp * 2 + 1) * 32 + l31]);

    // ---- store: O^T C/D lane = q-col -> out[b][c][qt64 + qhp*32 + l31] coalesced
    float* ob = out + (size_t)b * NC * NHW + qt64 + qhp * 32 + l31;
#pragma unroll
    for (int ci = 0; ci < 4; ++ci)
#pragma unroll
        for (int r = 0; r < 16; ++r) {
            int c = (ctb + ci) * 32 + (r & 3) + 8 * (r >> 2) + 4 * hi;
            ob[(size_t)c * NHW] = o[ci][r] * invq;
        }
}

extern "C" void kernel_launch(void* const* d_in, const int* in_sizes, int n_in,
                              void* d_out, int out_size, void* d_ws, size_t ws_size,
                              hipStream_t stream) {
    const float* l  = (const float*)d_in[0];
    const float* wt = (const float*)d_in[1];
    const float* wp = (const float*)d_in[2];
    float* out = (float*)d_out;

    char* ws = (char*)d_ws;
    unsigned short* Wbf = (unsigned short*)ws;                          // 131072 B
    unsigned short* Qbf = (unsigned short*)(ws + 131072);               // 8 MB
    unsigned short* Kbf = (unsigned short*)(ws + 131072 + 8388608);     // 8 MB
    unsigned short* Vbf = (unsigned short*)(ws + 131072 + 16777216);    // 16 MB

    hipLaunchKernelGGL(cast_w_kernel, dim3(256), dim3(256), 0, stream, wt, wp, Wbf);
    hipLaunchKernelGGL(proj_kernel,   dim3(512), dim3(256), 0, stream, l, Wbf, Qbf, Kbf, Vbf);
    hipLaunchKernelGGL(attn_kernel,   dim3(512), dim3(256), 0, stream, Qbf, Kbf, Vbf, out);
}